// Round 8
// baseline (741.454 us; speedup 1.0000x reference)
//
#include <hip/hip_runtime.h>
#include <stdint.h>

// ROUND 10 (resubmit -- infra failed twice, candidate never ran):
// R9 + __launch_bounds__(512,4) on attn_flash.
// R9 post-mortem: stg[8] T14 prefetch spilled (compiler's default 64-VGPR
// target for 512-thr blocks) -> 266 MB scratch writes, attn 410 us.
// min-waves=4/EU raises VGPR cap to 128 (matches the LDS-forced occupancy:
// 64 KB rl -> 2 blocks/CU = 16 waves = 4/EU), so stg stays in registers.
//
// K0 wtrans:   WT[z][k][o] = W_z[o][k] (in d_out, consumed before attn writes).
// K1 qkv_gemm: 256 thr, M=8 rows, thread = 4 consecutive o x 4 m.
// K2 attn_flash: block = (b, 4 q's), 8 waves = 8 heads, rl 64 KB swizzled:
//              word(qi,k,d) = qi*4096 + k*64 + (d&3) + 4*((d>>2)^(k&15)).

// ---------------------------------------------------------------- K0 ---
__global__ __launch_bounds__(256)
void wtrans(const float* __restrict__ Wq, const float* __restrict__ Wk,
            const float* __restrict__ Wv, float* __restrict__ WT)
{
    __shared__ float tile[64*65];
    const int z  = blockIdx.z;
    const float* W = (z==0) ? Wq : (z==1) ? Wk : Wv;
    const int kt = blockIdx.x * 64;
    const int ot = blockIdx.y * 64;
    const int t  = threadIdx.x;

    {
        const int c4 = (t & 15) * 4;
        #pragma unroll
        for (int i = 0; i < 4; i++) {
            const int r = (t >> 4) + i*16;
            const float4 v4 = *(const float4*)(W + (size_t)(ot + r)*512 + kt + c4);
            tile[r*65 + c4 + 0] = v4.x;
            tile[r*65 + c4 + 1] = v4.y;
            tile[r*65 + c4 + 2] = v4.z;
            tile[r*65 + c4 + 3] = v4.w;
        }
    }
    __syncthreads();
    {
        const int c4 = (t & 15) * 4;
        float* dst = WT + (size_t)z*262144;
        #pragma unroll
        for (int i = 0; i < 4; i++) {
            const int r2 = (t >> 4) + i*16;
            float4 v4;
            v4.x = tile[(c4+0)*65 + r2];
            v4.y = tile[(c4+1)*65 + r2];
            v4.z = tile[(c4+2)*65 + r2];
            v4.w = tile[(c4+3)*65 + r2];
            *(float4*)(dst + (size_t)(kt + r2)*512 + ot + c4) = v4;
        }
    }
}

// ---------------------------------------------------------------- K1 ---
__global__ __launch_bounds__(256)
void qkv_gemm(const float* __restrict__ X, const float* __restrict__ WT,
              const float* __restrict__ bq, const float* __restrict__ bk,
              const float* __restrict__ bv,
              float* __restrict__ qf, float* __restrict__ kTb, float* __restrict__ vf)
{
    __shared__ __align__(16) float Xs[8][512];      // 16 KB
    const int z  = blockIdx.y;
    const int m0 = blockIdx.x * 8;                  // 8-row tile (never crosses b)
    const float* WTz = WT + (size_t)z*262144;       // [512 k][512 o]
    const float* bb  = (z==0) ? bq : (z==1) ? bk : bv;

    const int t = threadIdx.x;
    {   // stage 8 X rows: thread t -> row t>>5, 16 consecutive floats
        const int r = t >> 5, c0 = (t & 31) * 16;
        const float4* src = (const float4*)(X + (size_t)(m0 + r)*512 + c0);
        float4* d4 = (float4*)(&Xs[r][c0]);
        d4[0]=src[0]; d4[1]=src[1]; d4[2]=src[2]; d4[3]=src[3];
    }
    __syncthreads();

    const int o0 = (t & 127) * 4;                   // 4 consecutive outputs
    const int mh = (t >> 7) * 4;                    // 4 rows: mh..mh+3
    float acc[4][4] = {};                           // [m][j]

    #pragma unroll 2
    for (int k = 0; k < 512; k += 4) {
        float4 w4[4];
        #pragma unroll
        for (int kk = 0; kk < 4; kk++)
            w4[kk] = *(const float4*)(WTz + (size_t)(k+kk)*512 + o0);  // b128 coalesced
        #pragma unroll
        for (int mm = 0; mm < 4; mm++) {
            const float4 x4 = *(const float4*)(&Xs[mh + mm][k]);       // uniform b128
            #pragma unroll
            for (int j = 0; j < 4; j++) {
                acc[mm][j] = fmaf(x4.x, ((const float*)&w4[0])[j], acc[mm][j]);
                acc[mm][j] = fmaf(x4.y, ((const float*)&w4[1])[j], acc[mm][j]);
                acc[mm][j] = fmaf(x4.z, ((const float*)&w4[2])[j], acc[mm][j]);
                acc[mm][j] = fmaf(x4.w, ((const float*)&w4[3])[j], acc[mm][j]);
            }
        }
    }

    const float4 b4 = *(const float4*)(bb + o0);
    const int b = m0 >> 9, lbase = (m0 & 511) + mh;
    const int h = o0 >> 6, d0 = o0 & 63;            // o0..o0+3 share h
    if (z == 1) {
        #pragma unroll
        for (int j = 0; j < 4; j++) {
            const float bj = ((const float*)&b4)[j];
            const float4 vv = make_float4(acc[0][j]+bj, acc[1][j]+bj,
                                          acc[2][j]+bj, acc[3][j]+bj);
            *(float4*)(kTb + ((size_t)(b*8 + h)*64 + d0 + j)*512 + lbase) = vv;
        }
    } else {
        float* dst = (z==0) ? qf : vf;
        #pragma unroll
        for (int mm = 0; mm < 4; mm++) {
            const float4 vv = make_float4(acc[mm][0]+b4.x, acc[mm][1]+b4.y,
                                          acc[mm][2]+b4.z, acc[mm][3]+b4.w);
            *(float4*)(dst + ((size_t)(b*8 + h)*512 + lbase + mm)*64 + d0) = vv;
        }
    }
}

// ---------------------------------------------------------------- K2 ---
__global__ __launch_bounds__(512, 4)   // 4 waves/EU min -> VGPR cap 128, no spill
void attn_flash(const float* __restrict__ qf, const float* __restrict__ kT,
                const float* __restrict__ vf, const float* __restrict__ rels,
                const float* __restrict__ heads, float* __restrict__ out)
{
    // rel tile [4 qi][64 k][64 d]; element (qi,k,d) at word
    //   qi*4096 + k*64 + (d&3) + 4*((d>>2) ^ (k&15))
    __shared__ __align__(16) float rl[4*64*64];     // 64 KB -> 2 blocks/CU

    // XCD-aware swizzle (512 = 8 XCD * 64, bijective)
    const int bid = blockIdx.x;
    const int wg  = (bid & 7) * 64 + (bid >> 3);
    const int b   = wg >> 7;
    const int q0  = (wg & 127) * 4;

    const int t = threadIdx.x, h = t >> 6, lane = t & 63;

    const float* kTh = kT + ((size_t)(b*8 + h)*64)*512;        // [64 d][512 l]
    const float* vfh = vf + ((size_t)(b*8 + h)*512)*64;        // [512 k][64 d]
    const float* qh  = qf + ((size_t)(b*8 + h)*512 + q0)*64;   // [4 qi][64 d]

    // phase-3 mapping: lane -> (qi=qp, d-quad=dq)
    const int qp = lane >> 4;                  // 0..3
    const int dq = lane & 15;                  // d = 4dq..4dq+3
    const float* vq = vfh + 4*dq;

    float ctx4[4] = {0.f, 0.f, 0.f, 0.f};      // ctx[qp][4dq..4dq+3]
    float m[4]   = {-3.0e38f, -3.0e38f, -3.0e38f, -3.0e38f};
    float s[4]   = {0.f, 0.f, 0.f, 0.f};

    // staging mapping: thread -> (qi, k-row, d-half)
    const int sqi = t >> 7;                    // 0..3
    const int su  = t & 127;
    const int sk  = su >> 1;                   // 0..63
    const int sdh = (su & 1) * 32;             // 0 or 32
    const int sc4 = sdh >> 2;                  // quad base: 0 or 8
    const int skx = sk & 15;
    const float* srcq = rels + ((size_t)(b*512 + q0 + sqi))*512*64
                             + (size_t)sk*64 + sdh;
    float* wb = rl + sqi*4096 + sk*64;

    // T14: preload tile 0 into registers (32 VGPR, fits under 128 cap)
    float4 stg[8];
    #pragma unroll
    for (int i = 0; i < 8; i++) stg[i] = *(const float4*)(srcq + 4*i);

    for (int kt = 0; kt < 8; kt++) {
        __syncthreads();                       // prev tile's PV done with rl
        #pragma unroll
        for (int i = 0; i < 8; i++)            // regs -> LDS (8x ds_write_b128)
            *(float4*)(wb + 4*((sc4 + i) ^ skx)) = stg[i];
        __syncthreads();                       // rl ready
        if (kt < 7) {                          // issue next tile's loads NOW;
            const float* nsrc = srcq + (size_t)(kt+1)*64*64;   // latency hides
            #pragma unroll                     // under phases 1-3
            for (int i = 0; i < 8; i++) stg[i] = *(const float4*)(nsrc + 4*i);
        }

        // ---- phase 1 score: lane = k within tile; rel reads b128
        const int kg = kt*64 + lane;
        const int kx4 = lane & 15;
        const float* rr = rl + lane*64;
        float sc[4] = {0.f, 0.f, 0.f, 0.f};
        #pragma unroll 4
        for (int d0 = 0; d0 < 64; d0 += 4) {
            const float k0 = kTh[(size_t)(d0+0)*512 + kg];     // coalesced
            const float k1 = kTh[(size_t)(d0+1)*512 + kg];
            const float k2 = kTh[(size_t)(d0+2)*512 + kg];
            const float k3 = kTh[(size_t)(d0+3)*512 + kg];
            #pragma unroll
            for (int qi = 0; qi < 4; qi++) {
                const float4 q4 = *(const float4*)(qh + (size_t)qi*64 + d0); // uniform
                const float4 r4 = *(const float4*)(rr + qi*4096
                                                   + 4*((d0 >> 2) ^ kx4));  // b128
                float a = sc[qi];
                a = fmaf(q4.x, k0, a);  a = fmaf(q4.x, r4.x, a);
                a = fmaf(q4.y, k1, a);  a = fmaf(q4.y, r4.y, a);
                a = fmaf(q4.z, k2, a);  a = fmaf(q4.z, r4.z, a);
                a = fmaf(q4.w, k3, a);  a = fmaf(q4.w, r4.w, a);
                sc[qi] = a;
            }
        }

        // ---- phase 2: online softmax update (lane = k; all-qi per lane)
        float P[4], al[4];
        #pragma unroll
        for (int qi = 0; qi < 4; qi++) {
            float S = sc[qi]*0.125f
                    + heads[((size_t)(b*512 + q0 + qi))*512 + kg];
            float mt = S;
            #pragma unroll
            for (int w = 1; w < 64; w <<= 1) mt = fmaxf(mt, __shfl_xor(mt, w));
            const float mn = fmaxf(m[qi], mt);
            al[qi] = __expf(m[qi] - mn);
            const float p  = __expf(S - mn);
            float ps = p;
            #pragma unroll
            for (int w = 1; w < 64; w <<= 1) ps += __shfl_xor(ps, w);
            s[qi] = s[qi]*al[qi] + ps;
            m[qi] = mn;
            P[qi] = p;
        }
        // rescale this lane's ctx by its qi's alpha
        const float alsel = (qp==0) ? al[0] : (qp==1) ? al[1]
                          : (qp==2) ? al[2] : al[3];
        ctx4[0] *= alsel; ctx4[1] *= alsel; ctx4[2] *= alsel; ctx4[3] *= alsel;

        // ---- phase 3 PV: lane = (qp, dq); rel reads b128
        const float* vt = vq + (size_t)(kt*64)*64;             // v[kt*64+kk][4dq..]
        const float* rbase = rl + qp*4096;
        #pragma unroll 8
        for (int kk = 0; kk < 64; kk++) {
            const float4 v4 = *(const float4*)(vt + (size_t)kk*64);
            const float4 r4 = *(const float4*)(rbase + kk*64 + 4*(dq ^ (kk & 15)));
            const float p0 = __int_as_float(
                __builtin_amdgcn_readlane(__float_as_int(P[0]), kk));
            const float p1 = __int_as_float(
                __builtin_amdgcn_readlane(__float_as_int(P[1]), kk));
            const float p2 = __int_as_float(
                __builtin_amdgcn_readlane(__float_as_int(P[2]), kk));
            const float p3 = __int_as_float(
                __builtin_amdgcn_readlane(__float_as_int(P[3]), kk));
            const float pk = (qp==0) ? p0 : (qp==1) ? p1 : (qp==2) ? p2 : p3;
            ctx4[0] = fmaf(pk, v4.x + r4.x, ctx4[0]);
            ctx4[1] = fmaf(pk, v4.y + r4.y, ctx4[1]);
            ctx4[2] = fmaf(pk, v4.z + r4.z, ctx4[2]);
            ctx4[3] = fmaf(pk, v4.w + r4.w, ctx4[3]);
        }
    }

    const float ssel = (qp==0) ? s[0] : (qp==1) ? s[1] : (qp==2) ? s[2] : s[3];
    const float inv = 1.f / ssel;
    const float4 o4 = make_float4(ctx4[0]*inv, ctx4[1]*inv, ctx4[2]*inv, ctx4[3]*inv);
    *(float4*)(out + ((size_t)(b*512 + q0 + qp))*512 + h*64 + 4*dq) = o4;
}

// --------------------------------------------------------------- launcher ---
extern "C" void kernel_launch(void* const* d_in, const int* in_sizes, int n_in,
                              void* d_out, int out_size, void* d_ws, size_t ws_size,
                              hipStream_t stream)
{
    (void)in_sizes; (void)n_in; (void)out_size; (void)ws_size;

    const float* hidden = (const float*)d_in[0];
    const float* heads  = (const float*)d_in[1];
    const float* rels   = (const float*)d_in[2];
    const float* Wq = (const float*)d_in[3];
    const float* bq = (const float*)d_in[4];
    const float* Wk = (const float*)d_in[5];
    const float* bk = (const float*)d_in[6];
    const float* Wv = (const float*)d_in[7];
    const float* bv = (const float*)d_in[8];
    float* outF = (float*)d_out;

    float* ws = (float*)d_ws;
    float* qf  = ws;                 // (B,H,L,DH) f32, 4 MB
    float* kTb = ws + 1048576;       // (B,H,DH,L) f32, 4 MB  (transposed K)
    float* vf  = ws + 2097152;       // (B,H,L,DH) f32, 4 MB; total 12 MB

    float* WT = outF;                // 3 MB in d_out, consumed before attn writes

    wtrans<<<dim3(8, 8, 3), 256, 0, stream>>>(Wq, Wk, Wv, WT);
    qkv_gemm<<<dim3(256, 3), 256, 0, stream>>>(hidden, WT, bq, bk, bv, qf, kTb, vf);
    attn_flash<<<dim3(512), 512, 0, stream>>>(qf, kTb, vf, rels, heads, outF);
}

// Round 9
// 633.603 us; speedup vs baseline: 1.1702x; 1.1702x over previous
//
#include <hip/hip_runtime.h>
#include <stdint.h>

// ROUND 11: compose the two HW-validated halves:
//   - R8's SYNCHRONOUS rel staging (load->ds_write in-loop; no cross-barrier
//     register prefetch -> no scratch. R9/R10's stg[8] prefetch allocated a
//     266 MB scratch array and launch_bounds couldn't stop it.)
//   - R10's phase-3 (qp,dq) remap: PV rel reads are 64x ds_read_b128 per
//     wave per tile (was 256x b32), float4 epilogue. Validated correct in R10.
//
// K0 wtrans:   WT[z][k][o] = W_z[o][k] (in d_out, consumed before attn writes).
// K1 qkv_gemm: 256 thr, M=8 rows, thread = 4 consecutive o x 4 m.
// K2 attn_flash: block = (b, 4 q's), 8 waves = 8 heads, rl 64 KB swizzled:
//              word(qi,k,d) = qi*4096 + k*64 + (d&3) + 4*((d>>2)^(k&15)).

// ---------------------------------------------------------------- K0 ---
__global__ __launch_bounds__(256)
void wtrans(const float* __restrict__ Wq, const float* __restrict__ Wk,
            const float* __restrict__ Wv, float* __restrict__ WT)
{
    __shared__ float tile[64*65];
    const int z  = blockIdx.z;
    const float* W = (z==0) ? Wq : (z==1) ? Wk : Wv;
    const int kt = blockIdx.x * 64;
    const int ot = blockIdx.y * 64;
    const int t  = threadIdx.x;

    {
        const int c4 = (t & 15) * 4;
        #pragma unroll
        for (int i = 0; i < 4; i++) {
            const int r = (t >> 4) + i*16;
            const float4 v4 = *(const float4*)(W + (size_t)(ot + r)*512 + kt + c4);
            tile[r*65 + c4 + 0] = v4.x;
            tile[r*65 + c4 + 1] = v4.y;
            tile[r*65 + c4 + 2] = v4.z;
            tile[r*65 + c4 + 3] = v4.w;
        }
    }
    __syncthreads();
    {
        const int c4 = (t & 15) * 4;
        float* dst = WT + (size_t)z*262144;
        #pragma unroll
        for (int i = 0; i < 4; i++) {
            const int r2 = (t >> 4) + i*16;
            float4 v4;
            v4.x = tile[(c4+0)*65 + r2];
            v4.y = tile[(c4+1)*65 + r2];
            v4.z = tile[(c4+2)*65 + r2];
            v4.w = tile[(c4+3)*65 + r2];
            *(float4*)(dst + (size_t)(kt + r2)*512 + ot + c4) = v4;
        }
    }
}

// ---------------------------------------------------------------- K1 ---
__global__ __launch_bounds__(256)
void qkv_gemm(const float* __restrict__ X, const float* __restrict__ WT,
              const float* __restrict__ bq, const float* __restrict__ bk,
              const float* __restrict__ bv,
              float* __restrict__ qf, float* __restrict__ kTb, float* __restrict__ vf)
{
    __shared__ __align__(16) float Xs[8][512];      // 16 KB
    const int z  = blockIdx.y;
    const int m0 = blockIdx.x * 8;                  // 8-row tile (never crosses b)
    const float* WTz = WT + (size_t)z*262144;       // [512 k][512 o]
    const float* bb  = (z==0) ? bq : (z==1) ? bk : bv;

    const int t = threadIdx.x;
    {   // stage 8 X rows: thread t -> row t>>5, 16 consecutive floats
        const int r = t >> 5, c0 = (t & 31) * 16;
        const float4* src = (const float4*)(X + (size_t)(m0 + r)*512 + c0);
        float4* d4 = (float4*)(&Xs[r][c0]);
        d4[0]=src[0]; d4[1]=src[1]; d4[2]=src[2]; d4[3]=src[3];
    }
    __syncthreads();

    const int o0 = (t & 127) * 4;                   // 4 consecutive outputs
    const int mh = (t >> 7) * 4;                    // 4 rows: mh..mh+3
    float acc[4][4] = {};                           // [m][j]

    #pragma unroll 2
    for (int k = 0; k < 512; k += 4) {
        float4 w4[4];
        #pragma unroll
        for (int kk = 0; kk < 4; kk++)
            w4[kk] = *(const float4*)(WTz + (size_t)(k+kk)*512 + o0);  // b128 coalesced
        #pragma unroll
        for (int mm = 0; mm < 4; mm++) {
            const float4 x4 = *(const float4*)(&Xs[mh + mm][k]);       // uniform b128
            #pragma unroll
            for (int j = 0; j < 4; j++) {
                acc[mm][j] = fmaf(x4.x, ((const float*)&w4[0])[j], acc[mm][j]);
                acc[mm][j] = fmaf(x4.y, ((const float*)&w4[1])[j], acc[mm][j]);
                acc[mm][j] = fmaf(x4.z, ((const float*)&w4[2])[j], acc[mm][j]);
                acc[mm][j] = fmaf(x4.w, ((const float*)&w4[3])[j], acc[mm][j]);
            }
        }
    }

    const float4 b4 = *(const float4*)(bb + o0);
    const int b = m0 >> 9, lbase = (m0 & 511) + mh;
    const int h = o0 >> 6, d0 = o0 & 63;            // o0..o0+3 share h
    if (z == 1) {
        #pragma unroll
        for (int j = 0; j < 4; j++) {
            const float bj = ((const float*)&b4)[j];
            const float4 vv = make_float4(acc[0][j]+bj, acc[1][j]+bj,
                                          acc[2][j]+bj, acc[3][j]+bj);
            *(float4*)(kTb + ((size_t)(b*8 + h)*64 + d0 + j)*512 + lbase) = vv;
        }
    } else {
        float* dst = (z==0) ? qf : vf;
        #pragma unroll
        for (int mm = 0; mm < 4; mm++) {
            const float4 vv = make_float4(acc[mm][0]+b4.x, acc[mm][1]+b4.y,
                                          acc[mm][2]+b4.z, acc[mm][3]+b4.w);
            *(float4*)(dst + ((size_t)(b*8 + h)*512 + lbase + mm)*64 + d0) = vv;
        }
    }
}

// ---------------------------------------------------------------- K2 ---
__global__ __launch_bounds__(512)
void attn_flash(const float* __restrict__ qf, const float* __restrict__ kT,
                const float* __restrict__ vf, const float* __restrict__ rels,
                const float* __restrict__ heads, float* __restrict__ out)
{
    // rel tile [4 qi][64 k][64 d]; element (qi,k,d) at word
    //   qi*4096 + k*64 + (d&3) + 4*((d>>2) ^ (k&15))
    __shared__ __align__(16) float rl[4*64*64];     // 64 KB -> 2 blocks/CU

    // XCD-aware swizzle (512 = 8 XCD * 64, bijective)
    const int bid = blockIdx.x;
    const int wg  = (bid & 7) * 64 + (bid >> 3);
    const int b   = wg >> 7;
    const int q0  = (wg & 127) * 4;

    const int t = threadIdx.x, h = t >> 6, lane = t & 63;

    const float* kTh = kT + ((size_t)(b*8 + h)*64)*512;        // [64 d][512 l]
    const float* vfh = vf + ((size_t)(b*8 + h)*512)*64;        // [512 k][64 d]
    const float* qh  = qf + ((size_t)(b*8 + h)*512 + q0)*64;   // [4 qi][64 d]

    // phase-3 mapping: lane -> (qi=qp, d-quad=dq)
    const int qp = lane >> 4;                  // 0..3
    const int dq = lane & 15;                  // d = 4dq..4dq+3
    const float* vq = vfh + 4*dq;

    float ctx4[4] = {0.f, 0.f, 0.f, 0.f};      // ctx[qp][4dq..4dq+3]
    float m[4]   = {-3.0e38f, -3.0e38f, -3.0e38f, -3.0e38f};
    float s[4]   = {0.f, 0.f, 0.f, 0.f};

    // staging mapping: thread -> (qi, k-row, d-half)
    const int sqi = t >> 7;                    // 0..3
    const int su  = t & 127;
    const int sk  = su >> 1;                   // 0..63
    const int sdh = (su & 1) * 32;             // 0 or 32
    const int sc4 = sdh >> 2;                  // quad base: 0 or 8
    const int skx = sk & 15;
    const float* srcq = rels + ((size_t)(b*512 + q0 + sqi))*512*64
                             + (size_t)sk*64 + sdh;
    float* wb = rl + sqi*4096 + sk*64;

    for (int kt = 0; kt < 8; kt++) {
        __syncthreads();                       // prev tile's PV done with rl
        {   // SYNC stage (R8 pattern: short live range, no scratch):
            // 128 B contiguous per thread from global, 8x ds_write_b128
            const float* src = srcq + (size_t)kt*4096;
            #pragma unroll
            for (int i = 0; i < 8; i++) {
                const float4 v4 = *(const float4*)(src + 4*i);
                *(float4*)(wb + 4*((sc4 + i) ^ skx)) = v4;
            }
        }
        __syncthreads();                       // rl ready

        // ---- phase 1 score: lane = k within tile; rel reads b128
        const int kg = kt*64 + lane;
        const int kx4 = lane & 15;
        const float* rr = rl + lane*64;
        float sc[4] = {0.f, 0.f, 0.f, 0.f};
        #pragma unroll 4
        for (int d0 = 0; d0 < 64; d0 += 4) {
            const float k0 = kTh[(size_t)(d0+0)*512 + kg];     // coalesced
            const float k1 = kTh[(size_t)(d0+1)*512 + kg];
            const float k2 = kTh[(size_t)(d0+2)*512 + kg];
            const float k3 = kTh[(size_t)(d0+3)*512 + kg];
            #pragma unroll
            for (int qi = 0; qi < 4; qi++) {
                const float4 q4 = *(const float4*)(qh + (size_t)qi*64 + d0); // uniform
                const float4 r4 = *(const float4*)(rr + qi*4096
                                                   + 4*((d0 >> 2) ^ kx4));  // b128
                float a = sc[qi];
                a = fmaf(q4.x, k0, a);  a = fmaf(q4.x, r4.x, a);
                a = fmaf(q4.y, k1, a);  a = fmaf(q4.y, r4.y, a);
                a = fmaf(q4.z, k2, a);  a = fmaf(q4.z, r4.z, a);
                a = fmaf(q4.w, k3, a);  a = fmaf(q4.w, r4.w, a);
                sc[qi] = a;
            }
        }

        // ---- phase 2: online softmax update (lane = k; all-qi per lane)
        float P[4], al[4];
        #pragma unroll
        for (int qi = 0; qi < 4; qi++) {
            float S = sc[qi]*0.125f
                    + heads[((size_t)(b*512 + q0 + qi))*512 + kg];
            float mt = S;
            #pragma unroll
            for (int w = 1; w < 64; w <<= 1) mt = fmaxf(mt, __shfl_xor(mt, w));
            const float mn = fmaxf(m[qi], mt);
            al[qi] = __expf(m[qi] - mn);
            const float p  = __expf(S - mn);
            float ps = p;
            #pragma unroll
            for (int w = 1; w < 64; w <<= 1) ps += __shfl_xor(ps, w);
            s[qi] = s[qi]*al[qi] + ps;
            m[qi] = mn;
            P[qi] = p;
        }
        // rescale this lane's ctx by its qi's alpha
        const float alsel = (qp==0) ? al[0] : (qp==1) ? al[1]
                          : (qp==2) ? al[2] : al[3];
        ctx4[0] *= alsel; ctx4[1] *= alsel; ctx4[2] *= alsel; ctx4[3] *= alsel;

        // ---- phase 3 PV: lane = (qp, dq); rel reads b128
        const float* vt = vq + (size_t)(kt*64)*64;             // v[kt*64+kk][4dq..]
        const float* rbase = rl + qp*4096;
        #pragma unroll 8
        for (int kk = 0; kk < 64; kk++) {
            const float4 v4 = *(const float4*)(vt + (size_t)kk*64);
            const float4 r4 = *(const float4*)(rbase + kk*64 + 4*(dq ^ (kk & 15)));
            const float p0 = __int_as_float(
                __builtin_amdgcn_readlane(__float_as_int(P[0]), kk));
            const float p1 = __int_as_float(
                __builtin_amdgcn_readlane(__float_as_int(P[1]), kk));
            const float p2 = __int_as_float(
                __builtin_amdgcn_readlane(__float_as_int(P[2]), kk));
            const float p3 = __int_as_float(
                __builtin_amdgcn_readlane(__float_as_int(P[3]), kk));
            const float pk = (qp==0) ? p0 : (qp==1) ? p1 : (qp==2) ? p2 : p3;
            ctx4[0] = fmaf(pk, v4.x + r4.x, ctx4[0]);
            ctx4[1] = fmaf(pk, v4.y + r4.y, ctx4[1]);
            ctx4[2] = fmaf(pk, v4.z + r4.z, ctx4[2]);
            ctx4[3] = fmaf(pk, v4.w + r4.w, ctx4[3]);
        }
    }

    const float ssel = (qp==0) ? s[0] : (qp==1) ? s[1] : (qp==2) ? s[2] : s[3];
    const float inv = 1.f / ssel;
    const float4 o4 = make_float4(ctx4[0]*inv, ctx4[1]*inv, ctx4[2]*inv, ctx4[3]*inv);
    *(float4*)(out + ((size_t)(b*512 + q0 + qp))*512 + h*64 + 4*dq) = o4;
}

// --------------------------------------------------------------- launcher ---
extern "C" void kernel_launch(void* const* d_in, const int* in_sizes, int n_in,
                              void* d_out, int out_size, void* d_ws, size_t ws_size,
                              hipStream_t stream)
{
    (void)in_sizes; (void)n_in; (void)out_size; (void)ws_size;

    const float* hidden = (const float*)d_in[0];
    const float* heads  = (const float*)d_in[1];
    const float* rels   = (const float*)d_in[2];
    const float* Wq = (const float*)d_in[3];
    const float* bq = (const float*)d_in[4];
    const float* Wk = (const float*)d_in[5];
    const float* bk = (const float*)d_in[6];
    const float* Wv = (const float*)d_in[7];
    const float* bv = (const float*)d_in[8];
    float* outF = (float*)d_out;

    float* ws = (float*)d_ws;
    float* qf  = ws;                 // (B,H,L,DH) f32, 4 MB
    float* kTb = ws + 1048576;       // (B,H,DH,L) f32, 4 MB  (transposed K)
    float* vf  = ws + 2097152;       // (B,H,L,DH) f32, 4 MB; total 12 MB

    float* WT = outF;                // 3 MB in d_out, consumed before attn writes

    wtrans<<<dim3(8, 8, 3), 256, 0, stream>>>(Wq, Wk, Wv, WT);
    qkv_gemm<<<dim3(256, 3), 256, 0, stream>>>(hidden, WT, bq, bk, bv, qf, kTb, vf);
    attn_flash<<<dim3(512), 512, 0, stream>>>(qf, kTb, vf, rels, heads, outF);
}